// Round 7
// baseline (895.384 us; speedup 1.0000x reference)
//
#include <hip/hip_runtime.h>
#include <math.h>

// Problem constants
#define HID 4096
#define NH  32
#define NKV 8
#define DH  128
#define SEQ 64
#define BS  16
#define MC  1024
#define QKV_N 6144                 // (NH + 2*NKV) * DH
#define NPAGES 64                  // MC / BS

// ---------------------------------------------------------------------------
// transpose64: in [64][K] row-major -> out [K][64]. Coalesced reads.
// ---------------------------------------------------------------------------
__global__ __launch_bounds__(256) void transpose64(const float* __restrict__ in,
                                                   float* __restrict__ out, int K) {
    int t = blockIdx.x * 256 + threadIdx.x;
    if (t >= SEQ * K) return;
    int h = t % K, s = t / K;               // t == s*K + h
    out[(size_t)h * SEQ + s] = in[t];
}

// ---------------------------------------------------------------------------
// gemm_t: Y[s][j] = sum_h XT[h][s] * W[j][h]   (Y = X @ W^T)
// XT: [K][64] f32 (pre-transposed). W: [N][K] f32. Y: [64][N] f32.
// lane = s (coalesced XT reads), j wave-uniform (broadcast W reads).
// ---------------------------------------------------------------------------
__global__ __launch_bounds__(256) void gemm_t(const float* __restrict__ XT,
                                              const float* __restrict__ W,
                                              float* __restrict__ Y,
                                              int N, int K) {
    int t = blockIdx.x * 256 + threadIdx.x;
    int lane = t & 63;
    int j = t >> 6;
    if (j >= N) return;
    const float* wr = W + (size_t)j * K;
    float a0 = 0.f, a1 = 0.f, a2 = 0.f, a3 = 0.f;
    for (int h = 0; h < K; h += 4) {
        a0 = fmaf(XT[(size_t)(h + 0) * SEQ + lane], wr[h + 0], a0);
        a1 = fmaf(XT[(size_t)(h + 1) * SEQ + lane], wr[h + 1], a1);
        a2 = fmaf(XT[(size_t)(h + 2) * SEQ + lane], wr[h + 2], a2);
        a3 = fmaf(XT[(size_t)(h + 3) * SEQ + lane], wr[h + 3], a3);
    }
    Y[(size_t)lane * N + j] = (a0 + a1) + (a2 + a3);
}

// ---------------------------------------------------------------------------
// Scalar RoPE in place on q (heads 0..31) and k (heads 32..39) of qkv.
// Thread per (s, h, i), i in [0,64): rotates pair (i, i+64).
// NOTE: sincosf(x, &sin, &cos) — SIN POINTER FIRST (this was the bug).
// ---------------------------------------------------------------------------
__global__ __launch_bounds__(256) void rope_scalar(float* __restrict__ qkv,
                                                   const int* __restrict__ ia,
                                                   const int* __restrict__ ib) {
    int t = blockIdx.x * 256 + threadIdx.x;
    if (t >= SEQ * (NH + NKV) * 64) return;
    int i = t & 63;
    int h = (t >> 6) % (NH + NKV);
    int s = t / ((NH + NKV) * 64);
    int pos = max(ia[s], ib[s]) - 1;
    float* base = qkv + (size_t)s * QKV_N + (size_t)h * DH;
    float ang = (float)pos / powf(10000.0f, (float)i * 2.0f / (float)DH);
    float sn, c;
    sincosf(ang, &sn, &c);   // FIXED: sin first, cos second
    float x1 = base[i];
    float x2 = base[i + 64];
    base[i]      = x1 * c - x2 * sn;
    base[i + 64] = x2 * c + x1 * sn;
}

// ---------------------------------------------------------------------------
// Scalar two-pass paged GQA attention. Block per (s, qhead); 128 threads.
// New-token K/V: read-time override at c == pos from qkv buffer.
// ---------------------------------------------------------------------------
__global__ __launch_bounds__(128) void attn_scalar(const float* __restrict__ qkv,
                                                   const float* __restrict__ k_cache,
                                                   const float* __restrict__ v_cache,
                                                   const int* __restrict__ ia,
                                                   const int* __restrict__ ib,
                                                   const int* __restrict__ block_tables,
                                                   float* __restrict__ attn_out) {
    __shared__ float sc[MC];
    __shared__ float red[128];

    int s  = blockIdx.x >> 5;      // / NH
    int qh = blockIdx.x & 31;      // % NH
    int kv = qh >> 2;
    int tid = threadIdx.x;

    int L   = max(ia[s], ib[s]);   // context_lens[s], order-immune
    int pos = L - 1;               // positions[s] == context_lens[s]-1 (probe-verified)

    const float* qrow = qkv + (size_t)s * QKV_N + (size_t)qh * DH;
    const float* knew = qkv + (size_t)s * QKV_N + (size_t)NH * DH + (size_t)kv * DH;
    const float* vnew = qkv + (size_t)s * QKV_N + (size_t)(NH + NKV) * DH + (size_t)kv * DH;
    const int* bt = block_tables + s * NPAGES;

    // Phase 1: scores
    for (int c = tid; c < L; c += 128) {
        const float* kr = (c == pos)
            ? knew
            : k_cache + ((size_t)bt[c >> 4] * BS + (c & 15)) * (size_t)(NKV * DH)
                      + (size_t)kv * DH;
        float acc = 0.f;
        for (int d = 0; d < DH; ++d) acc = fmaf(qrow[d], kr[d], acc);
        sc[c] = acc * 0.08838834764831845f;
    }
    __syncthreads();

    // Phase 2a: max
    float pm = -1e30f;
    for (int c = tid; c < L; c += 128) pm = fmaxf(pm, sc[c]);
    red[tid] = pm;
    __syncthreads();
    float m = -1e30f;
    for (int i = 0; i < 128; ++i) m = fmaxf(m, red[i]);
    __syncthreads();

    // Phase 2b: exp + sum (sc becomes unnormalized probs)
    float lp = 0.f;
    for (int c = tid; c < L; c += 128) {
        float p = expf(sc[c] - m);
        sc[c] = p;
        lp += p;
    }
    red[tid] = lp;
    __syncthreads();
    float l = 0.f;
    for (int i = 0; i < 128; ++i) l += red[i];
    float inv_l = 1.0f / l;
    __syncthreads();

    // Phase 3: PV, thread owns dim tid
    float o = 0.f;
    for (int c = 0; c < L; ++c) {
        const float* vr = (c == pos)
            ? vnew
            : v_cache + ((size_t)bt[c >> 4] * BS + (c & 15)) * (size_t)(NKV * DH)
                      + (size_t)kv * DH;
        o = fmaf(sc[c], vr[tid], o);
    }
    attn_out[(size_t)s * HID + (size_t)qh * DH + tid] = o * inv_l;
}

// ---------------------------------------------------------------------------
extern "C" void kernel_launch(void* const* d_in, const int* in_sizes, int n_in,
                              void* d_out, int out_size, void* d_ws, size_t ws_size,
                              hipStream_t stream) {
    // Resolve inputs by size (order-immune where sizes are unique).
    // k-first for the two 67M tensors (dict order: k_cache before v_cache).
    const float *hidden = nullptr, *k_cache = nullptr, *v_cache = nullptr;
    const float *qkv_w = nullptr, *o_w = nullptr;
    const int *i64a = nullptr, *i64b = nullptr, *block_tables = nullptr;
    for (int i = 0; i < n_in; ++i) {
        switch (in_sizes[i]) {
            case SEQ * HID:          hidden = (const float*)d_in[i]; break;   // 262144
            case 4096 * BS * NKV * DH:                                        // 67108864
                if (!k_cache) k_cache = (const float*)d_in[i];
                else          v_cache = (const float*)d_in[i];
                break;
            case QKV_N * HID:        qkv_w = (const float*)d_in[i]; break;    // 25165824
            case HID * HID:          o_w   = (const float*)d_in[i]; break;    // 16777216
            case SEQ * NPAGES:       block_tables = (const int*)d_in[i]; break; // 4096
            case SEQ:                                                          // 64
                if (!i64a) i64a = (const int*)d_in[i];
                else       i64b = (const int*)d_in[i];
                break;
        }
    }
    float* out = (float*)d_out;

    float* qkv  = (float*)d_ws;                        // 64*6144 f32 (1.5 MB)
    float* attn = qkv + (size_t)SEQ * QKV_N;           // 64*4096 f32 (1 MB)
    float* xt   = attn + (size_t)SEQ * HID;            // 4096*64 f32 (1 MB)

    // 1) hidden^T -> xt ; QKV projection -> qkv
    transpose64<<<(SEQ * HID) / 256, 256, 0, stream>>>(hidden, xt, HID);
    gemm_t<<<(SEQ * QKV_N) / 256, 256, 0, stream>>>(xt, qkv_w, qkv, QKV_N, HID);
    // 2) RoPE (q and k heads)
    rope_scalar<<<(SEQ * (NH + NKV) * 64) / 256, 256, 0, stream>>>(qkv, i64a, i64b);
    // 3) Attention -> attn
    attn_scalar<<<SEQ * NH, 128, 0, stream>>>(qkv, k_cache, v_cache,
                                              i64a, i64b, block_tables, attn);
    // 4) attn^T -> xt ; output projection -> out
    transpose64<<<(SEQ * HID) / 256, 256, 0, stream>>>(attn, xt, HID);
    gemm_t<<<(SEQ * HID) / 256, 256, 0, stream>>>(xt, o_w, out, HID, HID);
}

// Round 8
// 888.938 us; speedup vs baseline: 1.0073x; 1.0073x over previous
//
#include <hip/hip_runtime.h>
#include <math.h>

// Problem constants
#define HID 4096
#define NH  32
#define NKV 8
#define DH  128
#define SEQ 64
#define BS  16
#define MC  1024
#define QKV_N 6144                 // (NH + 2*NKV) * DH
#define NPAGES 64                  // MC / BS

// ---------------------------------------------------------------------------
// transpose64: in [64][K] row-major -> out [K][64]. Coalesced reads.
// ---------------------------------------------------------------------------
__global__ __launch_bounds__(256) void transpose64(const float* __restrict__ in,
                                                   float* __restrict__ out, int K) {
    int t = blockIdx.x * 256 + threadIdx.x;
    if (t >= SEQ * K) return;
    int h = t % K, s = t / K;               // t == s*K + h
    out[(size_t)h * SEQ + s] = in[t];
}

// ---------------------------------------------------------------------------
// gemm_t: Y[s][j] = sum_h XT[h][s] * W[j][h]   (Y = X @ W^T)
// XT: [K][64] f32 (pre-transposed). W: [N][K] f32. Y: [64][N] f32.
// lane = s (coalesced XT reads), j wave-uniform (broadcast W reads).
// ---------------------------------------------------------------------------
__global__ __launch_bounds__(256) void gemm_t(const float* __restrict__ XT,
                                              const float* __restrict__ W,
                                              float* __restrict__ Y,
                                              int N, int K) {
    int t = blockIdx.x * 256 + threadIdx.x;
    int lane = t & 63;
    int j = t >> 6;
    if (j >= N) return;
    const float* wr = W + (size_t)j * K;
    float a0 = 0.f, a1 = 0.f, a2 = 0.f, a3 = 0.f;
    for (int h = 0; h < K; h += 4) {
        a0 = fmaf(XT[(size_t)(h + 0) * SEQ + lane], wr[h + 0], a0);
        a1 = fmaf(XT[(size_t)(h + 1) * SEQ + lane], wr[h + 1], a1);
        a2 = fmaf(XT[(size_t)(h + 2) * SEQ + lane], wr[h + 2], a2);
        a3 = fmaf(XT[(size_t)(h + 3) * SEQ + lane], wr[h + 3], a3);
    }
    Y[(size_t)lane * N + j] = (a0 + a1) + (a2 + a3);
}

// ---------------------------------------------------------------------------
// Scalar RoPE in place on q (heads 0..31) and k (heads 32..39) of qkv.
// Thread per (s, h, i), i in [0,64): rotates pair (i, i+64).
// NOTE: sincosf(x, &sin, &cos) — SIN POINTER FIRST (this was the bug).
// ---------------------------------------------------------------------------
__global__ __launch_bounds__(256) void rope_scalar(float* __restrict__ qkv,
                                                   const int* __restrict__ ia,
                                                   const int* __restrict__ ib) {
    int t = blockIdx.x * 256 + threadIdx.x;
    if (t >= SEQ * (NH + NKV) * 64) return;
    int i = t & 63;
    int h = (t >> 6) % (NH + NKV);
    int s = t / ((NH + NKV) * 64);
    int pos = max(ia[s], ib[s]) - 1;
    float* base = qkv + (size_t)s * QKV_N + (size_t)h * DH;
    float ang = (float)pos / powf(10000.0f, (float)i * 2.0f / (float)DH);
    float sn, c;
    sincosf(ang, &sn, &c);   // FIXED: sin first, cos second
    float x1 = base[i];
    float x2 = base[i + 64];
    base[i]      = x1 * c - x2 * sn;
    base[i + 64] = x2 * c + x1 * sn;
}

// ---------------------------------------------------------------------------
// Scalar two-pass paged GQA attention. Block per (s, qhead); 128 threads.
// New-token K/V: read-time override at c == pos from qkv buffer.
// ---------------------------------------------------------------------------
__global__ __launch_bounds__(128) void attn_scalar(const float* __restrict__ qkv,
                                                   const float* __restrict__ k_cache,
                                                   const float* __restrict__ v_cache,
                                                   const int* __restrict__ ia,
                                                   const int* __restrict__ ib,
                                                   const int* __restrict__ block_tables,
                                                   float* __restrict__ attn_out) {
    __shared__ float sc[MC];
    __shared__ float red[128];

    int s  = blockIdx.x >> 5;      // / NH
    int qh = blockIdx.x & 31;      // % NH
    int kv = qh >> 2;
    int tid = threadIdx.x;

    int L   = max(ia[s], ib[s]);   // context_lens[s], order-immune
    int pos = L - 1;               // positions[s] == context_lens[s]-1 (probe-verified)

    const float* qrow = qkv + (size_t)s * QKV_N + (size_t)qh * DH;
    const float* knew = qkv + (size_t)s * QKV_N + (size_t)NH * DH + (size_t)kv * DH;
    const float* vnew = qkv + (size_t)s * QKV_N + (size_t)(NH + NKV) * DH + (size_t)kv * DH;
    const int* bt = block_tables + s * NPAGES;

    // Phase 1: scores
    for (int c = tid; c < L; c += 128) {
        const float* kr = (c == pos)
            ? knew
            : k_cache + ((size_t)bt[c >> 4] * BS + (c & 15)) * (size_t)(NKV * DH)
                      + (size_t)kv * DH;
        float acc = 0.f;
        for (int d = 0; d < DH; ++d) acc = fmaf(qrow[d], kr[d], acc);
        sc[c] = acc * 0.08838834764831845f;
    }
    __syncthreads();

    // Phase 2a: max
    float pm = -1e30f;
    for (int c = tid; c < L; c += 128) pm = fmaxf(pm, sc[c]);
    red[tid] = pm;
    __syncthreads();
    float m = -1e30f;
    for (int i = 0; i < 128; ++i) m = fmaxf(m, red[i]);
    __syncthreads();

    // Phase 2b: exp + sum (sc becomes unnormalized probs)
    float lp = 0.f;
    for (int c = tid; c < L; c += 128) {
        float p = expf(sc[c] - m);
        sc[c] = p;
        lp += p;
    }
    red[tid] = lp;
    __syncthreads();
    float l = 0.f;
    for (int i = 0; i < 128; ++i) l += red[i];
    float inv_l = 1.0f / l;
    __syncthreads();

    // Phase 3: PV, thread owns dim tid
    float o = 0.f;
    for (int c = 0; c < L; ++c) {
        const float* vr = (c == pos)
            ? vnew
            : v_cache + ((size_t)bt[c >> 4] * BS + (c & 15)) * (size_t)(NKV * DH)
                      + (size_t)kv * DH;
        o = fmaf(sc[c], vr[tid], o);
    }
    attn_out[(size_t)s * HID + (size_t)qh * DH + tid] = o * inv_l;
}

// ---------------------------------------------------------------------------
extern "C" void kernel_launch(void* const* d_in, const int* in_sizes, int n_in,
                              void* d_out, int out_size, void* d_ws, size_t ws_size,
                              hipStream_t stream) {
    // Resolve inputs by size (order-immune where sizes are unique).
    // k-first for the two 67M tensors (dict order: k_cache before v_cache).
    const float *hidden = nullptr, *k_cache = nullptr, *v_cache = nullptr;
    const float *qkv_w = nullptr, *o_w = nullptr;
    const int *i64a = nullptr, *i64b = nullptr, *block_tables = nullptr;
    for (int i = 0; i < n_in; ++i) {
        switch (in_sizes[i]) {
            case SEQ * HID:          hidden = (const float*)d_in[i]; break;   // 262144
            case 4096 * BS * NKV * DH:                                        // 67108864
                if (!k_cache) k_cache = (const float*)d_in[i];
                else          v_cache = (const float*)d_in[i];
                break;
            case QKV_N * HID:        qkv_w = (const float*)d_in[i]; break;    // 25165824
            case HID * HID:          o_w   = (const float*)d_in[i]; break;    // 16777216
            case SEQ * NPAGES:       block_tables = (const int*)d_in[i]; break; // 4096
            case SEQ:                                                          // 64
                if (!i64a) i64a = (const int*)d_in[i];
                else       i64b = (const int*)d_in[i];
                break;
        }
    }
    float* out = (float*)d_out;

    float* qkv  = (float*)d_ws;                        // 64*6144 f32 (1.5 MB)
    float* attn = qkv + (size_t)SEQ * QKV_N;           // 64*4096 f32 (1 MB)
    float* xt   = attn + (size_t)SEQ * HID;            // 4096*64 f32 (1 MB)

    // 1) hidden^T -> xt ; QKV projection -> qkv
    transpose64<<<(SEQ * HID) / 256, 256, 0, stream>>>(hidden, xt, HID);
    gemm_t<<<(SEQ * QKV_N) / 256, 256, 0, stream>>>(xt, qkv_w, qkv, QKV_N, HID);
    // 2) RoPE (q and k heads)
    rope_scalar<<<(SEQ * (NH + NKV) * 64) / 256, 256, 0, stream>>>(qkv, i64a, i64b);
    // 3) Attention -> attn
    attn_scalar<<<SEQ * NH, 128, 0, stream>>>(qkv, k_cache, v_cache,
                                              i64a, i64b, block_tables, attn);
    // 4) attn^T -> xt ; output projection -> out
    transpose64<<<(SEQ * HID) / 256, 256, 0, stream>>>(attn, xt, HID);
    gemm_t<<<(SEQ * HID) / 256, 256, 0, stream>>>(xt, o_w, out, HID, HID);
}

// Round 9
// 389.601 us; speedup vs baseline: 2.2982x; 2.2817x over previous
//
#include <hip/hip_runtime.h>
#include <math.h>

// Problem constants
#define HID 4096
#define NH  32
#define NKV 8
#define DH  128
#define SEQ 64
#define BS  16
#define MC  1024
#define QKV_N 6144                 // (NH + 2*NKV) * DH
#define NPAGES 64                  // MC / BS
#define KC  64                     // GEMM K-chunk (LDS tile depth)
#define KS  4                      // GEMM K-split factor

// Static device scratch (BSS) — proven safe in R5, immune to ws_size.
__device__ float g_qkv[SEQ * QKV_N];            // 1.5 MB
__device__ float g_attn[SEQ * HID];             // 1.0 MB
__device__ float g_part[KS * SEQ * QKV_N];      // 6.3 MB (shared by both GEMMs)

// ---------------------------------------------------------------------------
// Tiled GEMM with K-split: P[ks][s][j] = sum_{k in split ks} X[s][k]*W[j][k]
// Block tile: 64 s x 64 j. 256 threads (4 waves), thread = (tx: j quad, ty: s quad).
// LDS: transposed chunks Xs[k][s], Ws[k][j], stride 68 (16B-aligned, low conflict).
// Inner step: 2x ds_read_b128 + 16 v_fma_f32.
// ---------------------------------------------------------------------------
__global__ __launch_bounds__(256) void gemm_tile(const float* __restrict__ X,
                                                 const float* __restrict__ W,
                                                 float* __restrict__ P,
                                                 int N, int K) {
    __shared__ float Xs[KC][68];
    __shared__ float Ws[KC][68];
    const int tid = threadIdx.x;
    const int tx = tid & 15;          // j quad: columns 4*tx .. 4*tx+3
    const int ty = tid >> 4;          // s quad: rows    4*ty .. 4*ty+3
    const int jb = blockIdx.x * 64;
    const int ks = blockIdx.y;
    const int k_lo = ks * (K / KS);
    const int k_hi = k_lo + (K / KS);

    float4 a0 = {0,0,0,0}, a1 = {0,0,0,0}, a2 = {0,0,0,0}, a3 = {0,0,0,0};

    for (int k0 = k_lo; k0 < k_hi; k0 += KC) {
        // stage X chunk: 64 s x 64 k  (1024 float4, 4 per thread), transpose to Xs[k][s]
        #pragma unroll
        for (int r = 0; r < 4; ++r) {
            int idx = r * 256 + tid;
            int s  = idx >> 4;
            int k4 = idx & 15;
            float4 v = *(const float4*)(X + (size_t)s * K + k0 + k4 * 4);
            Xs[k4 * 4 + 0][s] = v.x;
            Xs[k4 * 4 + 1][s] = v.y;
            Xs[k4 * 4 + 2][s] = v.z;
            Xs[k4 * 4 + 3][s] = v.w;
        }
        // stage W chunk: 64 j x 64 k, transpose to Ws[k][j]
        #pragma unroll
        for (int r = 0; r < 4; ++r) {
            int idx = r * 256 + tid;
            int j  = idx >> 4;
            int k4 = idx & 15;
            float4 v = *(const float4*)(W + (size_t)(jb + j) * K + k0 + k4 * 4);
            Ws[k4 * 4 + 0][j] = v.x;
            Ws[k4 * 4 + 1][j] = v.y;
            Ws[k4 * 4 + 2][j] = v.z;
            Ws[k4 * 4 + 3][j] = v.w;
        }
        __syncthreads();
        #pragma unroll
        for (int kk = 0; kk < KC; ++kk) {
            float4 xv = *(const float4*)(&Xs[kk][ty * 4]);
            float4 wv = *(const float4*)(&Ws[kk][tx * 4]);
            a0.x = fmaf(xv.x, wv.x, a0.x); a0.y = fmaf(xv.x, wv.y, a0.y);
            a0.z = fmaf(xv.x, wv.z, a0.z); a0.w = fmaf(xv.x, wv.w, a0.w);
            a1.x = fmaf(xv.y, wv.x, a1.x); a1.y = fmaf(xv.y, wv.y, a1.y);
            a1.z = fmaf(xv.y, wv.z, a1.z); a1.w = fmaf(xv.y, wv.w, a1.w);
            a2.x = fmaf(xv.z, wv.x, a2.x); a2.y = fmaf(xv.z, wv.y, a2.y);
            a2.z = fmaf(xv.z, wv.z, a2.z); a2.w = fmaf(xv.z, wv.w, a2.w);
            a3.x = fmaf(xv.w, wv.x, a3.x); a3.y = fmaf(xv.w, wv.y, a3.y);
            a3.z = fmaf(xv.w, wv.z, a3.z); a3.w = fmaf(xv.w, wv.w, a3.w);
        }
        __syncthreads();
    }
    // write partials: P[ks][s][j], 4 s-rows x float4
    float* pb = P + (size_t)ks * SEQ * N;
    *(float4*)(pb + (size_t)(ty * 4 + 0) * N + jb + tx * 4) = a0;
    *(float4*)(pb + (size_t)(ty * 4 + 1) * N + jb + tx * 4) = a1;
    *(float4*)(pb + (size_t)(ty * 4 + 2) * N + jb + tx * 4) = a2;
    *(float4*)(pb + (size_t)(ty * 4 + 3) * N + jb + tx * 4) = a3;
}

// ---------------------------------------------------------------------------
// reduce_ks: Y[i] = sum over KS splits of P[ks][i]; float4 per thread.
// n4 = 64*N/4.
// ---------------------------------------------------------------------------
__global__ __launch_bounds__(256) void reduce_ks(const float* __restrict__ P,
                                                 float* __restrict__ Y, int n4) {
    int t = blockIdx.x * 256 + threadIdx.x;
    if (t >= n4) return;
    const float4* p4 = (const float4*)P;
    float4 a = p4[t];
    float4 b = p4[t + n4];
    float4 c = p4[t + 2 * n4];
    float4 d = p4[t + 3 * n4];
    float4 r;
    r.x = (a.x + b.x) + (c.x + d.x);
    r.y = (a.y + b.y) + (c.y + d.y);
    r.z = (a.z + b.z) + (c.z + d.z);
    r.w = (a.w + b.w) + (c.w + d.w);
    ((float4*)Y)[t] = r;
}

// ---------------------------------------------------------------------------
// Scalar RoPE in place on q (heads 0..31) and k (heads 32..39) of qkv.
// sincosf(x, &sin, &cos) — sin pointer FIRST.
// ---------------------------------------------------------------------------
__global__ __launch_bounds__(256) void rope_scalar(float* __restrict__ qkv,
                                                   const int* __restrict__ ia,
                                                   const int* __restrict__ ib) {
    int t = blockIdx.x * 256 + threadIdx.x;
    if (t >= SEQ * (NH + NKV) * 64) return;
    int i = t & 63;
    int h = (t >> 6) % (NH + NKV);
    int s = t / ((NH + NKV) * 64);
    int pos = max(ia[s], ib[s]) - 1;
    float* base = qkv + (size_t)s * QKV_N + (size_t)h * DH;
    float ang = (float)pos / powf(10000.0f, (float)i * 2.0f / (float)DH);
    float sn, c;
    sincosf(ang, &sn, &c);
    float x1 = base[i];
    float x2 = base[i + 64];
    base[i]      = x1 * c - x2 * sn;
    base[i + 64] = x2 * c + x1 * sn;
}

// ---------------------------------------------------------------------------
// Scalar two-pass paged GQA attention (unchanged from passing R6 version).
// ---------------------------------------------------------------------------
__global__ __launch_bounds__(128) void attn_scalar(const float* __restrict__ qkv,
                                                   const float* __restrict__ k_cache,
                                                   const float* __restrict__ v_cache,
                                                   const int* __restrict__ ia,
                                                   const int* __restrict__ ib,
                                                   const int* __restrict__ block_tables,
                                                   float* __restrict__ attn_out) {
    __shared__ float sc[MC];
    __shared__ float red[128];

    int s  = blockIdx.x >> 5;
    int qh = blockIdx.x & 31;
    int kv = qh >> 2;
    int tid = threadIdx.x;

    int L   = max(ia[s], ib[s]);
    int pos = L - 1;

    const float* qrow = qkv + (size_t)s * QKV_N + (size_t)qh * DH;
    const float* knew = qkv + (size_t)s * QKV_N + (size_t)NH * DH + (size_t)kv * DH;
    const float* vnew = qkv + (size_t)s * QKV_N + (size_t)(NH + NKV) * DH + (size_t)kv * DH;
    const int* bt = block_tables + s * NPAGES;

    for (int c = tid; c < L; c += 128) {
        const float* kr = (c == pos)
            ? knew
            : k_cache + ((size_t)bt[c >> 4] * BS + (c & 15)) * (size_t)(NKV * DH)
                      + (size_t)kv * DH;
        float acc = 0.f;
        for (int d = 0; d < DH; ++d) acc = fmaf(qrow[d], kr[d], acc);
        sc[c] = acc * 0.08838834764831845f;
    }
    __syncthreads();

    float pm = -1e30f;
    for (int c = tid; c < L; c += 128) pm = fmaxf(pm, sc[c]);
    red[tid] = pm;
    __syncthreads();
    float m = -1e30f;
    for (int i = 0; i < 128; ++i) m = fmaxf(m, red[i]);
    __syncthreads();

    float lp = 0.f;
    for (int c = tid; c < L; c += 128) {
        float p = expf(sc[c] - m);
        sc[c] = p;
        lp += p;
    }
    red[tid] = lp;
    __syncthreads();
    float l = 0.f;
    for (int i = 0; i < 128; ++i) l += red[i];
    float inv_l = 1.0f / l;
    __syncthreads();

    float o = 0.f;
    for (int c = 0; c < L; ++c) {
        const float* vr = (c == pos)
            ? vnew
            : v_cache + ((size_t)bt[c >> 4] * BS + (c & 15)) * (size_t)(NKV * DH)
                      + (size_t)kv * DH;
        o = fmaf(sc[c], vr[tid], o);
    }
    attn_out[(size_t)s * HID + (size_t)qh * DH + tid] = o * inv_l;
}

// ---------------------------------------------------------------------------
extern "C" void kernel_launch(void* const* d_in, const int* in_sizes, int n_in,
                              void* d_out, int out_size, void* d_ws, size_t ws_size,
                              hipStream_t stream) {
    // Resolve inputs by size (order-immune; k-first for the two 67M tensors).
    const float *hidden = nullptr, *k_cache = nullptr, *v_cache = nullptr;
    const float *qkv_w = nullptr, *o_w = nullptr;
    const int *i64a = nullptr, *i64b = nullptr, *block_tables = nullptr;
    for (int i = 0; i < n_in; ++i) {
        switch (in_sizes[i]) {
            case SEQ * HID:          hidden = (const float*)d_in[i]; break;
            case 4096 * BS * NKV * DH:
                if (!k_cache) k_cache = (const float*)d_in[i];
                else          v_cache = (const float*)d_in[i];
                break;
            case QKV_N * HID:        qkv_w = (const float*)d_in[i]; break;
            case HID * HID:          o_w   = (const float*)d_in[i]; break;
            case SEQ * NPAGES:       block_tables = (const int*)d_in[i]; break;
            case SEQ:
                if (!i64a) i64a = (const int*)d_in[i];
                else       i64b = (const int*)d_in[i];
                break;
        }
    }
    float* out = (float*)d_out;

    static float* qkv_p  = nullptr;
    static float* attn_p = nullptr;
    static float* part_p = nullptr;
    if (!qkv_p) {
        void* p;
        hipGetSymbolAddress(&p, HIP_SYMBOL(g_qkv));  qkv_p  = (float*)p;
        hipGetSymbolAddress(&p, HIP_SYMBOL(g_attn)); attn_p = (float*)p;
        hipGetSymbolAddress(&p, HIP_SYMBOL(g_part)); part_p = (float*)p;
    }

    // 1) QKV projection: X=hidden (64x4096), W=qkv_w (6144x4096) -> g_qkv
    gemm_tile<<<dim3(QKV_N / 64, KS), 256, 0, stream>>>(hidden, qkv_w, part_p,
                                                        QKV_N, HID);
    reduce_ks<<<(SEQ * QKV_N / 4 + 255) / 256, 256, 0, stream>>>(part_p, qkv_p,
                                                                 SEQ * QKV_N / 4);
    // 2) RoPE (q and k heads)
    rope_scalar<<<(SEQ * (NH + NKV) * 64) / 256, 256, 0, stream>>>(qkv_p, i64a, i64b);
    // 3) Attention -> g_attn
    attn_scalar<<<SEQ * NH, 128, 0, stream>>>(qkv_p, k_cache, v_cache,
                                              i64a, i64b, block_tables, attn_p);
    // 4) Output projection: X=g_attn (64x4096), W=o_w (4096x4096) -> out
    gemm_tile<<<dim3(HID / 64, KS), 256, 0, stream>>>(attn_p, o_w, part_p,
                                                      HID, HID);
    reduce_ks<<<(SEQ * HID / 4 + 255) / 256, 256, 0, stream>>>(part_p, out,
                                                               SEQ * HID / 4);
}